// Round 2
// baseline (409.989 us; speedup 1.0000x reference)
//
#include <hip/hip_runtime.h>
#include <stdint.h>

#define NPTS 131072
#define DIM  512
#define KC   512
#define NKT  16          // DIM / 32

typedef float f32x16 __attribute__((ext_vector_type(16)));
typedef float f32x4  __attribute__((ext_vector_type(4)));
typedef short bf16x8 __attribute__((ext_vector_type(8)));

// round-to-nearest-even fp32 -> bf16 (bit pattern in short)
__device__ __forceinline__ short f2bf(float f) {
  union { float f; unsigned u; } v; v.f = f;
  unsigned r = v.u + 0x7FFFu + ((v.u >> 16) & 1u);
  return (short)(r >> 16);
}

__device__ __forceinline__ bf16x8 pack8(f32x4 a, f32x4 b) {
  bf16x8 p;
  p[0] = f2bf(a.x); p[1] = f2bf(a.y); p[2] = f2bf(a.z); p[3] = f2bf(a.w);
  p[4] = f2bf(b.x); p[5] = f2bf(b.y); p[6] = f2bf(b.z); p[7] = f2bf(b.w);
  return p;
}

__device__ __forceinline__ float sq8(f32x4 a, f32x4 b) {
  return a.x*a.x + a.y*a.y + a.z*a.z + a.w*a.w
       + b.x*b.x + b.y*b.y + b.z*b.z + b.w*b.w;
}

// ---------------------------------------------------------------------------
// Pre-kernel: clusters fp32 [512][512] -> bf16 row-major (plain layout; B is
// consumed via L2-resident global reads, no LDS -> no swizzle needed).
// Also c2[n] = ||c_n||^2 in fp32.  512 blocks x 64 threads.
// ---------------------------------------------------------------------------
__global__ void dec_pack(const float* __restrict__ C, short* __restrict__ Bbf,
                         float* __restrict__ c2) {
  const int n    = blockIdx.x;
  const int lane = threadIdx.x;          // 0..63, 8 floats each
  const float* src = C + (size_t)n * DIM + lane * 8;
  f32x4 v0 = *(const f32x4*)src;
  f32x4 v1 = *(const f32x4*)(src + 4);
  float s = sq8(v0, v1);
  #pragma unroll
  for (int m = 1; m < 64; m <<= 1) s += __shfl_xor(s, m, 64);
  if (lane == 0) c2[n] = s;
  *(bf16x8*)(Bbf + (size_t)n * DIM + lane * 8) = pack8(v0, v1);
}

// ---------------------------------------------------------------------------
// Main fused kernel — barrier-free main loop.
// Block = 256 threads = 4 waves; block tile 32 rows x 512 cols (full K width).
// Wave wn covers cols wn*128 .. wn*128+127 via 4 x mfma_f32_32x32x16_bf16
// (wave tile 32x128, acc = 4 x f32x16).
// A fragments: read straight from X (each lane owns row row0+l31, k-half h;
//   full 128B/row/kt touched -> line-granular; 4x wn reuse hits L1/L2).
//   fp32->bf16 convert + x2 accumulation fused in-register.
// B fragments: read straight from the 512 KB L2-resident bf16 cluster matrix.
// All loads use fixed base + immediate offsets (kt*128B <= 1920 < 4096).
// Epilogue: q = rcp(1+d2), lane-butterfly row sums, one barrier to combine
// the 4 wn partials through 512 B of LDS, normalize, coalesced stores.
// ---------------------------------------------------------------------------
__global__ __launch_bounds__(256, 3)
void dec_main(const float* __restrict__ X, const short* __restrict__ Bbf,
              const float* __restrict__ c2g, float* __restrict__ out) {
  __shared__ float part[4][2][16];

  const int tid  = threadIdx.x;
  const int lane = tid & 63;
  const int wn   = tid >> 6;    // 0..3 : column quarter
  const int l31  = lane & 31;
  const int h    = lane >> 5;   // k-half of MFMA operand
  const int row0 = blockIdx.x * 32;

  // per-lane base pointers (h-dependent part folded in once)
  const float* ap = X + (size_t)(row0 + l31) * DIM + h * 8;
  const short* bp[4];
  #pragma unroll
  for (int nt = 0; nt < 4; ++nt)
    bp[nt] = Bbf + (size_t)(wn * 128 + nt * 32 + l31) * DIM + h * 8;

  f32x16 acc[4];
  #pragma unroll
  for (int nt = 0; nt < 4; ++nt) acc[nt] = (f32x16)0.f;

  float x2 = 0.f;

  // ---- barrier-free K loop: k = kt*32 + ks*16 + h*8 ----
  #pragma unroll 4
  for (int kt = 0; kt < NKT; ++kt) {
    const int ko = kt * 32;                 // float offset for this K-step
    // A: 8 floats per ks  (ks=0: +0, ks=1: +16)
    f32x4 a00 = *(const f32x4*)(ap + ko);
    f32x4 a01 = *(const f32x4*)(ap + ko + 4);
    f32x4 a10 = *(const f32x4*)(ap + ko + 16);
    f32x4 a11 = *(const f32x4*)(ap + ko + 20);
    // B: 16 B per (nt, ks)
    bf16x8 b0[4], b1[4];
    #pragma unroll
    for (int nt = 0; nt < 4; ++nt) {
      b0[nt] = *(const bf16x8*)(bp[nt] + ko);
      b1[nt] = *(const bf16x8*)(bp[nt] + ko + 16);
    }

    bf16x8 af0 = pack8(a00, a01);
    bf16x8 af1 = pack8(a10, a11);
    x2 += sq8(a00, a01) + sq8(a10, a11);

    #pragma unroll
    for (int nt = 0; nt < 4; ++nt)
      acc[nt] = __builtin_amdgcn_mfma_f32_32x32x16_bf16(af0, b0[nt], acc[nt], 0, 0, 0);
    #pragma unroll
    for (int nt = 0; nt < 4; ++nt)
      acc[nt] = __builtin_amdgcn_mfma_f32_32x32x16_bf16(af1, b1[nt], acc[nt], 0, 0, 0);
  }

  // complete row norm: lane h=0/h=1 each hold half of row (row0+l31)
  x2 += __shfl_xor(x2, 32, 64);

  float c2v[4];
  #pragma unroll
  for (int nt = 0; nt < 4; ++nt) c2v[nt] = c2g[wn * 128 + nt * 32 + l31];

  // ---- q = 1/(1+d2), per-row partial sums over this wave's 128 cols ----
  float srow[16];
  #pragma unroll
  for (int r = 0; r < 16; ++r) {
    const int mbase = (r & 3) + 8 * (r >> 2);
    // x2 of output row m = mbase + 4*h lives in lane (mbase + 4*h)
    const float x2m = __shfl(x2, mbase + 4 * h, 64);
    float s = 0.f;
    #pragma unroll
    for (int nt = 0; nt < 4; ++nt) {
      float d2 = fmaxf(x2m + c2v[nt] - 2.f * acc[nt][r], 0.f);
      float q = __builtin_amdgcn_rcpf(1.f + d2);
      acc[nt][r] = q;
      s += q;
    }
    // butterfly over the 32 col-lanes (masks < 32 keep the two h-rows apart)
    #pragma unroll
    for (int msk = 1; msk < 32; msk <<= 1) s += __shfl_xor(s, msk, 64);
    srow[r] = s;
  }

  if (l31 == 0) {
    #pragma unroll
    for (int r = 0; r < 16; ++r) part[wn][h][r] = srow[r];
  }
  __syncthreads();

  // ---- normalize + store ----
  #pragma unroll
  for (int r = 0; r < 16; ++r) {
    const float tot = part[0][h][r] + part[1][h][r] + part[2][h][r] + part[3][h][r];
    const float iv = __builtin_amdgcn_rcpf(tot);
    const int m = (r & 3) + 8 * (r >> 2) + 4 * h;
    float* o = out + (size_t)(row0 + m) * KC + wn * 128 + l31;
    #pragma unroll
    for (int nt = 0; nt < 4; ++nt)
      o[nt * 32] = acc[nt][r] * iv;
  }
}

extern "C" void kernel_launch(void* const* d_in, const int* in_sizes, int n_in,
                              void* d_out, int out_size, void* d_ws, size_t ws_size,
                              hipStream_t stream) {
  const float* X = (const float*)d_in[0];   // inputs  [131072, 512] fp32
  const float* C = (const float*)d_in[1];   // clusters [512, 512] fp32
  float* out = (float*)d_out;               // [131072, 512] fp32

  short* Bbf = (short*)d_ws;                                  // 512 KB bf16 clusters
  float* c2  = (float*)((char*)d_ws + (size_t)KC * DIM * 2);  // 2 KB cluster norms

  dec_pack<<<KC, 64, 0, stream>>>(C, Bbf, c2);
  dec_main<<<NPTS / 32, 256, 0, stream>>>(X, Bbf, c2, out);
}

// Round 3
// 272.542 us; speedup vs baseline: 1.5043x; 1.5043x over previous
//
#include <hip/hip_runtime.h>
#include <stdint.h>

#define NPTS 131072
#define DIM  512
#define KC   512
#define NKT  16          // DIM / 32
#define BM   64          // rows per block (2 m-waves x 32)

typedef float f32x16 __attribute__((ext_vector_type(16)));
typedef float f32x4  __attribute__((ext_vector_type(4)));
typedef short bf16x8 __attribute__((ext_vector_type(8)));
typedef short bf16x4 __attribute__((ext_vector_type(4)));

// round-to-nearest-even fp32 -> bf16 (bit pattern in short)
__device__ __forceinline__ short f2bf(float f) {
  union { float f; unsigned u; } v; v.f = f;
  unsigned r = v.u + 0x7FFFu + ((v.u >> 16) & 1u);
  return (short)(r >> 16);
}

__device__ __forceinline__ bf16x8 pack8(f32x4 a, f32x4 b) {
  bf16x8 p;
  p[0] = f2bf(a.x); p[1] = f2bf(a.y); p[2] = f2bf(a.z); p[3] = f2bf(a.w);
  p[4] = f2bf(b.x); p[5] = f2bf(b.y); p[6] = f2bf(b.z); p[7] = f2bf(b.w);
  return p;
}

__device__ __forceinline__ bf16x4 pack4(f32x4 a) {
  bf16x4 p;
  p[0] = f2bf(a.x); p[1] = f2bf(a.y); p[2] = f2bf(a.z); p[3] = f2bf(a.w);
  return p;
}

__device__ __forceinline__ float sq4(f32x4 a) {
  return a.x*a.x + a.y*a.y + a.z*a.z + a.w*a.w;
}

// ---------------------------------------------------------------------------
// Pre-kernel: clusters fp32 [512][512] -> bf16, packed in EXACT fragment-
// consumption order: Bp[kt][wn][nt][ks][lane(=h*32+l31)] x bf16x8, so the
// main kernel's B-fragment load is a contiguous, fully-coalesced 1 KB per
// wave-instruction (and stays L2-resident: 512 KB total).
// Also c2[n] = ||c_n||^2 (fp32).  512 blocks x 64 threads; block n = row n.
// ---------------------------------------------------------------------------
__global__ void dec_pack(const float* __restrict__ C, short* __restrict__ Bp,
                         float* __restrict__ c2) {
  const int n    = blockIdx.x;
  const int lane = threadIdx.x;          // 0..63, 8 floats each
  const float* src = C + (size_t)n * DIM + lane * 8;
  f32x4 v0 = *(const f32x4*)src;
  f32x4 v1 = *(const f32x4*)(src + 4);
  float s = sq4(v0) + sq4(v1);
  #pragma unroll
  for (int m = 1; m < 64; m <<= 1) s += __shfl_xor(s, m, 64);
  if (lane == 0) c2[n] = s;
  // this lane holds B[n][k], k = lane*8 .. +8
  const int kt = lane >> 2;              // k / 32
  const int ks = (lane >> 1) & 1;        // (k%32) / 16
  const int hh = lane & 1;               // (k%16) / 8  -> fragment k-half
  const int wn = n >> 7, nt = (n >> 5) & 3, r = n & 31;
  const size_t off =
      ((((size_t)(kt * 4 + wn) * 4 + nt) * 2 + ks) * 64 + (hh * 32 + r)) * 8;
  *(bf16x8*)(Bp + off) = pack8(v0, v1);
}

// ---------------------------------------------------------------------------
// Main fused kernel — NO barriers in the K loop.
// Block = 512 threads = 8 waves (wm = wave>>2 in {0,1}, wn = wave&3).
// Block tile 64 rows x 512 cols (full K width -> block-local normalization).
// Wave tile 32 x 128 via 4 x mfma_f32_32x32x16_bf16 (acc = 4 x f32x16).
//
// A path (per wave, wave-private => same-wave DS ordering, no syncthreads):
//   lane l, j=0..3: load f32x4 of row (l>>3)+8j, floats (l&7)*4 of the kt
//   slice — 8 lanes cover one full 128B row-slice => 8 fully-used lines per
//   instruction. Convert->bf16 (x2 fused), ds_write_b64 into a 2 KB
//   wave-private buffer with 16B-chunk XOR swizzle p^=(row>>1)&3
//   (conflict-free at the 4-sweep floor), ds_read_b128 the MFMA fragments.
// B path: contiguous 1 KB fragment loads from the pre-packed L2-resident Bp.
// Epilogue: q = rcp(1+d2), butterfly row-sums, 1 barrier to combine the 4
// wn partials, normalize, coalesced stores.
// ---------------------------------------------------------------------------
__global__ __launch_bounds__(512, 4)
void dec_main(const float* __restrict__ X, const short* __restrict__ Bp,
              const float* __restrict__ c2g, float* __restrict__ out) {
  __shared__ short Apriv[8][2][1024];     // 8 waves x dbuf x 2KB
  __shared__ float x2ws[8][32];
  __shared__ float part[2][4][2][16];

  const int tid  = threadIdx.x;
  const int lane = tid & 63;
  const int wave = tid >> 6;
  const int wm   = wave >> 2;   // 0..1
  const int wn   = wave & 3;    // 0..3
  const int l31  = lane & 31;
  const int h    = lane >> 5;
  const int wrow0 = blockIdx.x * BM + wm * 32;   // wave's first row

  // A global base: lane covers rows (lane>>3)+8j, float chunk (lane&7)*4
  const float* aB = X + (size_t)(wrow0 + (lane >> 3)) * DIM + (lane & 7) * 4;

  // B fragment base: Bp[kt][wn][nt][ks][lane] x 8 shorts
  const short* bB = Bp + (size_t)wn * (4 * 2 * 64 * 8) + lane * 8;
  // strides (shorts): kt: 16384, nt: 1024, ks: 512

  // LDS offsets (in shorts, 32 shorts per row)
  const int sigma = (lane >> 4) & 3;     // ((row>>1)&3 for row=(lane>>3)+8j)
  const int wbase = ((lane >> 3) * 32) + ((((lane & 7) >> 1) ^ sigma) << 3) +
                    (lane & 1) * 4;      // + j*256
  int rdoff[2];
  #pragma unroll
  for (int ks = 0; ks < 2; ++ks)
    rdoff[ks] = l31 * 32 + (((ks * 2 + h) ^ ((l31 >> 1) & 3)) << 3);

  f32x16 acc[4];
  #pragma unroll
  for (int nt = 0; nt < 4; ++nt) acc[nt] = (f32x16)0.f;
  float x2s[4] = {0.f, 0.f, 0.f, 0.f};

  // ---- barrier-free K loop ----
  #pragma unroll 2
  for (int kt = 0; kt < NKT; ++kt) {
    short* abuf = &Apriv[wave][kt & 1][0];

    // coalesced A loads (4 x f32x4, each instr = 8 fully-used 128B lines)
    f32x4 av[4];
    #pragma unroll
    for (int j = 0; j < 4; ++j)
      av[j] = *(const f32x4*)(aB + kt * 32 + (size_t)j * 8 * DIM);

    // coalesced B fragment loads (8 x 1KB contiguous, L2-resident)
    bf16x8 bfr[2][4];
    #pragma unroll
    for (int ks = 0; ks < 2; ++ks)
      #pragma unroll
      for (int nt = 0; nt < 4; ++nt)
        bfr[ks][nt] = *(const bf16x8*)(bB + kt * 16384 + nt * 1024 + ks * 512);

    // convert + x2 + stage into wave-private LDS (swizzled, conflict-free)
    #pragma unroll
    for (int j = 0; j < 4; ++j) {
      x2s[j] += sq4(av[j]);
      *(bf16x4*)(abuf + wbase + j * 256) = pack4(av[j]);
    }

    // fragment reads (same wave => ordered after the writes, no barrier)
    bf16x8 af[2];
    #pragma unroll
    for (int ks = 0; ks < 2; ++ks)
      af[ks] = *(const bf16x8*)(abuf + rdoff[ks]);

    #pragma unroll
    for (int ks = 0; ks < 2; ++ks)
      #pragma unroll
      for (int nt = 0; nt < 4; ++nt)
        acc[nt] = __builtin_amdgcn_mfma_f32_32x32x16_bf16(
            af[ks], bfr[ks][nt], acc[nt], 0, 0, 0);
  }

  // ---- row norms: reduce the 8 chunk-partials per row, park in LDS ----
  #pragma unroll
  for (int j = 0; j < 4; ++j) {
    x2s[j] += __shfl_xor(x2s[j], 1, 64);
    x2s[j] += __shfl_xor(x2s[j], 2, 64);
    x2s[j] += __shfl_xor(x2s[j], 4, 64);
  }
  if ((lane & 7) == 0) {
    #pragma unroll
    for (int j = 0; j < 4; ++j) x2ws[wave][(lane >> 3) + 8 * j] = x2s[j];
  }

  float c2v[4];
  #pragma unroll
  for (int nt = 0; nt < 4; ++nt) c2v[nt] = c2g[wn * 128 + nt * 32 + l31];

  // ---- q = 1/(1+d2), per-row partial sums over this wave's 128 cols ----
  float srow[16];
  #pragma unroll
  for (int r = 0; r < 16; ++r) {
    const int mloc = (r & 3) + 8 * (r >> 2) + 4 * h;
    const float x2m = x2ws[wave][mloc];
    float s = 0.f;
    #pragma unroll
    for (int nt = 0; nt < 4; ++nt) {
      float d2 = fmaxf(x2m + c2v[nt] - 2.f * acc[nt][r], 0.f);
      float q = __builtin_amdgcn_rcpf(1.f + d2);
      acc[nt][r] = q;
      s += q;
    }
    #pragma unroll
    for (int msk = 1; msk < 32; msk <<= 1) s += __shfl_xor(s, msk, 64);
    srow[r] = s;
  }

  if (l31 == 0) {
    #pragma unroll
    for (int r = 0; r < 16; ++r) part[wm][wn][h][r] = srow[r];
  }
  __syncthreads();

  // ---- normalize + store ----
  #pragma unroll
  for (int r = 0; r < 16; ++r) {
    const float tot = part[wm][0][h][r] + part[wm][1][h][r] +
                      part[wm][2][h][r] + part[wm][3][h][r];
    const float iv = __builtin_amdgcn_rcpf(tot);
    const int mloc = (r & 3) + 8 * (r >> 2) + 4 * h;
    float* o = out + (size_t)(wrow0 + mloc) * KC + wn * 128 + l31;
    #pragma unroll
    for (int nt = 0; nt < 4; ++nt)
      o[nt * 32] = acc[nt][r] * iv;
  }
}

extern "C" void kernel_launch(void* const* d_in, const int* in_sizes, int n_in,
                              void* d_out, int out_size, void* d_ws, size_t ws_size,
                              hipStream_t stream) {
  const float* X = (const float*)d_in[0];   // inputs  [131072, 512] fp32
  const float* C = (const float*)d_in[1];   // clusters [512, 512] fp32
  float* out = (float*)d_out;               // [131072, 512] fp32

  short* Bp = (short*)d_ws;                                   // 512 KB packed bf16 clusters
  float* c2 = (float*)((char*)d_ws + (size_t)KC * DIM * 2);   // 2 KB cluster norms

  dec_pack<<<KC, 64, 0, stream>>>(C, Bp, c2);
  dec_main<<<NPTS / BM, 512, 0, stream>>>(X, Bp, c2, out);
}

// Round 4
// 203.434 us; speedup vs baseline: 2.0153x; 1.3397x over previous
//
#include <hip/hip_runtime.h>
#include <stdint.h>

#define NPTS 131072
#define DIM  512
#define KC   512
#define BM   32
#define BK   16
#define NKT  32          // DIM / BK

typedef float f32x16 __attribute__((ext_vector_type(16)));
typedef float f32x4  __attribute__((ext_vector_type(4)));
typedef float f32x2  __attribute__((ext_vector_type(2)));
typedef short bf16x8 __attribute__((ext_vector_type(8)));
typedef short bf16x2 __attribute__((ext_vector_type(2)));

// round-to-nearest-even fp32 -> bf16 (bit pattern in short)
__device__ __forceinline__ short f2bf(float f) {
  union { float f; unsigned u; } v; v.f = f;
  unsigned r = v.u + 0x7FFFu + ((v.u >> 16) & 1u);
  return (short)(r >> 16);
}

__device__ __forceinline__ bf16x8 pack8(f32x4 a, f32x4 b) {
  bf16x8 p;
  p[0] = f2bf(a.x); p[1] = f2bf(a.y); p[2] = f2bf(a.z); p[3] = f2bf(a.w);
  p[4] = f2bf(b.x); p[5] = f2bf(b.y); p[6] = f2bf(b.z); p[7] = f2bf(b.w);
  return p;
}

__device__ __forceinline__ float sq4(f32x4 a) {
  return a.x*a.x + a.y*a.y + a.z*a.z + a.w*a.w;
}

__device__ __forceinline__ void gload_lds16(const short* g, short* l) {
  __builtin_amdgcn_global_load_lds(
      (const __attribute__((address_space(1))) unsigned int*)g,
      (__attribute__((address_space(3))) unsigned int*)l, 16, 0, 0);
}

// ---------------------------------------------------------------------------
// Pre-kernel: clusters fp32 [512][512] -> bf16 packed in EXACT MFMA-fragment
// order per BK=16 K-step: 16B slot index = ((kt*4 + wn)*4 + nt)*64 + h*32 + r
// where n = wn*128 + nt*32 + r, k = kt*16 + h*8 + j. The main kernel stages
// each 16 KB kt-tile linearly with global_load_lds and reads fragments at
// base + lane*16 (conflict-free). Also c2[n] = ||c_n||^2 (fp32).
// 512 blocks x 64 threads; block n handles cluster row n.
// ---------------------------------------------------------------------------
__global__ void dec_pack(const float* __restrict__ C, short* __restrict__ Bp,
                         float* __restrict__ c2) {
  const int n    = blockIdx.x;
  const int lane = threadIdx.x;          // covers k = lane*8 .. +7
  const float* src = C + (size_t)n * DIM + lane * 8;
  f32x4 v0 = *(const f32x4*)src;
  f32x4 v1 = *(const f32x4*)(src + 4);
  float s = sq4(v0) + sq4(v1);
  #pragma unroll
  for (int m = 1; m < 64; m <<= 1) s += __shfl_xor(s, m, 64);
  if (lane == 0) c2[n] = s;
  const int kt = lane >> 1;              // k / 16
  const int h  = lane & 1;               // (k>>3)&1
  const int wn = n >> 7, nt = (n >> 5) & 3, r = n & 31;
  const size_t slot = ((size_t)(kt * 4 + wn) * 4 + nt) * 64 + h * 32 + r;
  *(bf16x8*)(Bp + slot * 8) = pack8(v0, v1);
}

// ---------------------------------------------------------------------------
// Main fused kernel.
// 256 threads = 4 waves (wn = wave), block tile 32 rows x 512 cols (full
// cluster width -> block-local normalization). Wave tile 32x128 via
// 4 x mfma_f32_32x32x16_bf16 (acc = 4 x f32x16 = 64 AGPR).
// ~35 KB LDS -> 4 blocks/CU; regs ~104 -> 4 waves/SIMD -> 16 waves/CU in
// 4 INDEPENDENT barrier domains (covers each domain's barrier drain).
//
// Pipeline (1 barrier per kt):
//   iter kt: stage B(kt+1) via global_load_lds (linear, pre-packed frag
//   order); ds_write A(kt+1) from regs loaded at iter kt-1 (2 iters in
//   flight); issue A(kt+3) load; ds_read frags of kt (base+lane*16, linear,
//   conflict-free); 4 MFMA; barrier.
// A global loads: 8 threads/row x f32x2 = 64B contiguous per row-slice;
// the 128B line is completed by the next kt (L1-resident, 16KB set/CU).
// Epilogue: q = rcp(1+d2), butterfly row-sums, combine 4 wn partials in LDS,
// normalize, coalesced stores.
// ---------------------------------------------------------------------------
__global__ __launch_bounds__(256, 4)
void dec_main(const float* __restrict__ X, const short* __restrict__ Bp,
              const float* __restrict__ c2g, float* __restrict__ out) {
  __shared__ short Bbuf[2][KC * BK];     // 2 x 16 KB
  __shared__ short Abuf[2][BM * BK];     // 2 x 1 KB
  __shared__ float x2sh[BM];
  __shared__ float part[4][BM];
  __shared__ float rowinv[BM];

  const int tid  = threadIdx.x;
  const int lane = tid & 63;
  const int wn   = tid >> 6;    // wave = column quarter
  const int l31  = lane & 31;
  const int h    = lane >> 5;
  const int row0 = blockIdx.x * BM;

  // ---- A staging role: thread -> (row, float-pair) ----
  const int arow = tid >> 3;            // 0..31
  const int acol = tid & 7;             // float pair index (floats acol*2..+1)
  const float* aptr = X + (size_t)(row0 + arow) * DIM + acol * 2;
  // fragment-order LDS offset (shorts): frag_lane = h_a*32 + arow, j = (acol&3)*2
  const int awoff = (((acol >> 2) * 32 + arow) << 3) + ((acol & 3) << 1);

  // ---- B staging: 4 sweeps of 16B/thread, linear ----
  const short* bsrc = Bp + tid * 8;     // + kt*8192 + sweep*2048

  f32x16 acc[4];
  #pragma unroll
  for (int nt = 0; nt < 4; ++nt) acc[nt] = (f32x16)0.f;
  float x2a = 0.f;

  // ---- prologue: stage kt=0; prime the A pipeline (A0 write, A1/A2 in regs)
  {
    #pragma unroll
    for (int sw = 0; sw < 4; ++sw)
      gload_lds16(bsrc + sw * 2048, &Bbuf[0][sw * 2048 + tid * 8]);
    f32x2 a0 = *(const f32x2*)(aptr);
    x2a += a0.x * a0.x + a0.y * a0.y;
    bf16x2 p; p[0] = f2bf(a0.x); p[1] = f2bf(a0.y);
    *(bf16x2*)&Abuf[0][awoff] = p;
  }
  f32x2 av_w = *(const f32x2*)(aptr + 1 * BK);   // A(1): written at kt=0
  f32x2 av_p = *(const f32x2*)(aptr + 2 * BK);   // A(2): in flight
  __syncthreads();

  // ---- K loop: one barrier per kt ----
  #pragma unroll 2
  for (int kt = 0; kt < NKT; ++kt) {
    const int cur = kt & 1, nxt = cur ^ 1;

    if (kt + 1 < NKT) {
      // stage next B tile (async, drains at the barrier)
      #pragma unroll
      for (int sw = 0; sw < 4; ++sw)
        gload_lds16(bsrc + (size_t)(kt + 1) * 8192 + sw * 2048,
                    &Bbuf[nxt][sw * 2048 + tid * 8]);
      // write A(kt+1) (loaded 2 iters ago -> latency long covered)
      x2a += av_w.x * av_w.x + av_w.y * av_w.y;
      bf16x2 p; p[0] = f2bf(av_w.x); p[1] = f2bf(av_w.y);
      *(bf16x2*)&Abuf[nxt][awoff] = p;
      av_w = av_p;
      const int kpre = (kt + 3 < NKT) ? (kt + 3) : (NKT - 1);
      av_p = *(const f32x2*)(aptr + kpre * BK);
    }

    // fragment reads: all linear (base + lane*16), conflict-free
    bf16x8 af = *(const bf16x8*)&Abuf[cur][lane * 8];
    bf16x8 bfr[4];
    #pragma unroll
    for (int nt = 0; nt < 4; ++nt)
      bfr[nt] = *(const bf16x8*)&Bbuf[cur][(wn * 4 + nt) * 512 + lane * 8];

    #pragma unroll
    for (int nt = 0; nt < 4; ++nt)
      acc[nt] = __builtin_amdgcn_mfma_f32_32x32x16_bf16(af, bfr[nt], acc[nt], 0, 0, 0);

    __syncthreads();
  }

  // ---- row norms: 8 thread-partials per row, lanes (l&7) within wave ----
  x2a += __shfl_xor(x2a, 1, 64);
  x2a += __shfl_xor(x2a, 2, 64);
  x2a += __shfl_xor(x2a, 4, 64);
  if ((tid & 7) == 0) x2sh[arow] = x2a;
  __syncthreads();

  float c2v[4];
  #pragma unroll
  for (int nt = 0; nt < 4; ++nt) c2v[nt] = c2g[wn * 128 + nt * 32 + l31];

  // ---- q = rcp(1+d2), per-row partial sums over this wave's 128 cols ----
  float srow[16];
  #pragma unroll
  for (int r = 0; r < 16; ++r) {
    const int row = (r & 3) + 8 * (r >> 2) + 4 * h;
    const float x2m = x2sh[row];
    float s = 0.f;
    #pragma unroll
    for (int nt = 0; nt < 4; ++nt) {
      float d2 = fmaxf(x2m + c2v[nt] - 2.f * acc[nt][r], 0.f);
      float q = __builtin_amdgcn_rcpf(1.f + d2);
      acc[nt][r] = q;
      s += q;
    }
    #pragma unroll
    for (int msk = 1; msk < 32; msk <<= 1) s += __shfl_xor(s, msk, 64);
    srow[r] = s;
  }

  if (l31 == 0) {
    #pragma unroll
    for (int r = 0; r < 16; ++r)
      part[wn][(r & 3) + 8 * (r >> 2) + 4 * h] = srow[r];
  }
  __syncthreads();
  if (tid < BM)
    rowinv[tid] = __builtin_amdgcn_rcpf(part[0][tid] + part[1][tid] +
                                        part[2][tid] + part[3][tid]);
  __syncthreads();

  // ---- normalize + coalesced stores ----
  #pragma unroll
  for (int r = 0; r < 16; ++r) {
    const int row = (r & 3) + 8 * (r >> 2) + 4 * h;
    const float iv = rowinv[row];
    float* o = out + (size_t)(row0 + row) * KC + wn * 128 + l31;
    #pragma unroll
    for (int nt = 0; nt < 4; ++nt)
      o[nt * 32] = acc[nt][r] * iv;
  }
}

extern "C" void kernel_launch(void* const* d_in, const int* in_sizes, int n_in,
                              void* d_out, int out_size, void* d_ws, size_t ws_size,
                              hipStream_t stream) {
  const float* X = (const float*)d_in[0];   // inputs  [131072, 512] fp32
  const float* C = (const float*)d_in[1];   // clusters [512, 512] fp32
  float* out = (float*)d_out;               // [131072, 512] fp32

  short* Bp = (short*)d_ws;                                   // 512 KB packed bf16 clusters
  float* c2 = (float*)((char*)d_ws + (size_t)KC * DIM * 2);   // 2 KB cluster norms

  dec_pack<<<KC, 64, 0, stream>>>(C, Bp, c2);
  dec_main<<<NPTS / BM, 256, 0, stream>>>(X, Bp, c2, out);
}

// Round 5
// 177.512 us; speedup vs baseline: 2.3096x; 1.1460x over previous
//
#include <hip/hip_runtime.h>
#include <stdint.h>

#define NPTS 131072
#define DIM  512
#define KC   512
#define BM   64
#define BK   32
#define NKT  16          // DIM / BK

typedef float f32x16 __attribute__((ext_vector_type(16)));
typedef float f32x4  __attribute__((ext_vector_type(4)));
typedef short bf16x8 __attribute__((ext_vector_type(8)));
typedef short bf16x4 __attribute__((ext_vector_type(4)));

// round-to-nearest-even fp32 -> bf16 (bit pattern in short)
__device__ __forceinline__ short f2bf(float f) {
  union { float f; unsigned u; } v; v.f = f;
  unsigned r = v.u + 0x7FFFu + ((v.u >> 16) & 1u);
  return (short)(r >> 16);
}

__device__ __forceinline__ bf16x8 pack8(f32x4 a, f32x4 b) {
  bf16x8 p;
  p[0] = f2bf(a.x); p[1] = f2bf(a.y); p[2] = f2bf(a.z); p[3] = f2bf(a.w);
  p[4] = f2bf(b.x); p[5] = f2bf(b.y); p[6] = f2bf(b.z); p[7] = f2bf(b.w);
  return p;
}

__device__ __forceinline__ bf16x4 pack4(f32x4 a) {
  bf16x4 p;
  p[0] = f2bf(a.x); p[1] = f2bf(a.y); p[2] = f2bf(a.z); p[3] = f2bf(a.w);
  return p;
}

__device__ __forceinline__ float sq4(f32x4 a) {
  return a.x*a.x + a.y*a.y + a.z*a.z + a.w*a.w;
}

__device__ __forceinline__ void gload_lds16(const short* g, short* l) {
  __builtin_amdgcn_global_load_lds(
      (const __attribute__((address_space(1))) unsigned int*)g,
      (__attribute__((address_space(3))) unsigned int*)l, 16, 0, 0);
}

// ---------------------------------------------------------------------------
// Pre-kernel: clusters fp32 [512][512] -> bf16 packed in MFMA-fragment order
// for BK=32 K-steps. 16B slot = (((kt*2+s)*4 + wn)*4 + nt)*64 + h*32 + r
// where n = wn*128+nt*32+r, k = kt*32 + s*16 + h*8 + j. Each 32 KB kt-tile is
// contiguous -> the main kernel stages it linearly with global_load_lds and
// reads fragments at base + lane*16 (conflict-free).
// Also c2[n] = ||c_n||^2 (fp32). 512 blocks x 64 threads, block n = row n.
// ---------------------------------------------------------------------------
__global__ void dec_pack(const float* __restrict__ C, short* __restrict__ Bp,
                         float* __restrict__ c2) {
  const int n    = blockIdx.x;
  const int lane = threadIdx.x;          // covers k = lane*8 .. +7
  const float* src = C + (size_t)n * DIM + lane * 8;
  f32x4 v0 = *(const f32x4*)src;
  f32x4 v1 = *(const f32x4*)(src + 4);
  float s = sq4(v0) + sq4(v1);
  #pragma unroll
  for (int m = 1; m < 64; m <<= 1) s += __shfl_xor(s, m, 64);
  if (lane == 0) c2[n] = s;
  const int kt = lane >> 2;              // k / 32
  const int st = (lane >> 1) & 1;        // (k>>4)&1
  const int hh = lane & 1;               // (k>>3)&1
  const int wn = n >> 7, nt = (n >> 5) & 3, r = n & 31;
  const size_t slot =
      (((size_t)(kt * 2 + st) * 4 + wn) * 4 + nt) * 64 + hh * 32 + r;
  *(bf16x8*)(Bp + slot * 8) = pack8(v0, v1);
}

// ---------------------------------------------------------------------------
// Main fused kernel.
// 512 threads = 8 waves (wm = wave>>2, wn = wave&3); block tile 64 x 512
// (full cluster width -> block-local normalization). Wave tile 32x128 via
// 4 x mfma_f32_32x32x16_bf16 per k-substep, 2 substeps per kt (BK=32).
// LDS = 64 KB Bbuf + 8 KB Abuf + ~1.5 KB epi = 73.5 KB -> 2 blocks/CU
// (2 independent barrier domains); regs ~124 -> 4 waves/SIMD -> 16 waves/CU.
//
// Iteration (one barrier per kt), issue order chosen so the barrier's
// vmcnt(0) drain only meets OLD loads:
//   [barrier] -> issue A-prefetch f32x4 (for kt+3; drained at age ~1 iter)
//   -> issue 4 B-stage global_load_lds (kt+1 tile; L2-resident source)
//   -> pack+ds_write A(kt+1) from regs loaded 2 iters ago (x2 fused, exact
//      fp32) -> 2 x (frag ds_reads + 4 MFMA) -> barrier.
// A global loads: one dwordx4 per thread per kt = 8 rows x 128 B per wave
// instr, every line fully used (BK=32 fp32 = exactly one cache line/row).
// ---------------------------------------------------------------------------
__global__ __launch_bounds__(512, 4)
void dec_main(const float* __restrict__ X, const short* __restrict__ Bp,
              const float* __restrict__ c2g, float* __restrict__ out) {
  __shared__ short Bbuf[2][KC * BK];       // 2 x 32 KB
  __shared__ short Abuf[2][2 * 2 * BM * 8];// 2 x 4 KB, [s][h][row][8]
  __shared__ float x2sh[BM];
  __shared__ float part[4][BM];
  __shared__ float rowinv[BM];

  const int tid  = threadIdx.x;
  const int lane = tid & 63;
  const int wave = tid >> 6;
  const int wm   = wave >> 2;   // 0..1 : row half
  const int wn   = wave & 3;    // 0..3 : column quarter
  const int l31  = lane & 31;
  const int h    = lane >> 5;
  const int row0 = blockIdx.x * BM;

  // ---- A staging role: thread -> (row, k-chunk) ----
  const int arow = tid >> 3;            // 0..63
  const int ac   = tid & 7;             // chunk of 4 floats: k = ac*4..+3
  const float* aptr = X + (size_t)(row0 + arow) * DIM + ac * 4;
  // frag-order LDS offset (shorts): s=ac>>2, h=(ac>>1)&1, j0=(ac&1)*4
  const int awoff = (((ac >> 2) * 2 + ((ac >> 1) & 1)) * BM + arow) * 8 +
                    (ac & 1) * 4;

  // ---- B staging: 4 sweeps of 16B/thread, linear ----
  const short* bsrc = Bp + tid * 8;     // + kt*16384 + sweep*4096 (shorts)

  f32x16 acc[4];
  #pragma unroll
  for (int nt = 0; nt < 4; ++nt) acc[nt] = (f32x16)0.f;
  float x2a = 0.f;

  // ---- prologue: stage B(0), write A(0), prime A(1)/A(2) regs ----
  {
    #pragma unroll
    for (int sw = 0; sw < 4; ++sw)
      gload_lds16(bsrc + sw * 4096, &Bbuf[0][sw * 4096 + tid * 8]);
    f32x4 a0 = *(const f32x4*)(aptr);
    x2a += sq4(a0);
    *(bf16x4*)&Abuf[0][awoff] = pack4(a0);
  }
  f32x4 av_w = *(const f32x4*)(aptr + 1 * BK);   // A(1): written at kt=0
  f32x4 av_p = *(const f32x4*)(aptr + 2 * BK);   // A(2): in flight
  __syncthreads();

  // ---- K loop: one barrier per kt ----
  for (int kt = 0; kt < NKT; ++kt) {
    const int cur = kt & 1, nxt = cur ^ 1;

    if (kt + 1 < NKT) {
      // (1) A prefetch for kt+3 FIRST -> old by the time the drain hits it
      const int kpre = (kt + 3 < NKT) ? (kt + 3) : (NKT - 1);
      f32x4 av_n = *(const f32x4*)(aptr + kpre * BK);
      // (2) stage next B tile (L2-resident source, linear dest)
      #pragma unroll
      for (int sw = 0; sw < 4; ++sw)
        gload_lds16(bsrc + (size_t)(kt + 1) * 16384 + sw * 4096,
                    &Bbuf[nxt][sw * 4096 + tid * 8]);
      // (3) write A(kt+1) from regs loaded 2 iterations ago
      x2a += sq4(av_w);
      *(bf16x4*)&Abuf[nxt][awoff] = pack4(av_w);
      av_w = av_p;
      av_p = av_n;
    }

    // (4) compute: 2 k-substeps of 16, all frag reads linear (base+lane*16)
    #pragma unroll
    for (int s = 0; s < 2; ++s) {
      bf16x8 af = *(const bf16x8*)
          &Abuf[cur][((s * 2 + h) * BM + wm * 32 + l31) * 8];
      bf16x8 bfr[4];
      #pragma unroll
      for (int nt = 0; nt < 4; ++nt)
        bfr[nt] = *(const bf16x8*)
            &Bbuf[cur][((s * 4 + wn) * 4 + nt) * 512 + lane * 8];
      #pragma unroll
      for (int nt = 0; nt < 4; ++nt)
        acc[nt] = __builtin_amdgcn_mfma_f32_32x32x16_bf16(
            af, bfr[nt], acc[nt], 0, 0, 0);
    }

    __syncthreads();
  }

  // ---- row norms: 8 chunk-partials per row live in lanes (lane&7) ----
  x2a += __shfl_xor(x2a, 1, 64);
  x2a += __shfl_xor(x2a, 2, 64);
  x2a += __shfl_xor(x2a, 4, 64);
  if ((tid & 7) == 0) x2sh[arow] = x2a;
  __syncthreads();

  float c2v[4];
  #pragma unroll
  for (int nt = 0; nt < 4; ++nt) c2v[nt] = c2g[wn * 128 + nt * 32 + l31];

  // ---- q = rcp(1+d2), per-row partial sums over this wave's 128 cols ----
  float srow[16];
  #pragma unroll
  for (int r = 0; r < 16; ++r) {
    const int mloc = (r & 3) + 8 * (r >> 2) + 4 * h;   // row within wave tile
    const float x2m = x2sh[wm * 32 + mloc];
    float s = 0.f;
    #pragma unroll
    for (int nt = 0; nt < 4; ++nt) {
      float d2 = fmaxf(x2m + c2v[nt] - 2.f * acc[nt][r], 0.f);
      float q = __builtin_amdgcn_rcpf(1.f + d2);
      acc[nt][r] = q;
      s += q;
    }
    #pragma unroll
    for (int msk = 1; msk < 32; msk <<= 1) s += __shfl_xor(s, msk, 64);
    srow[r] = s;
  }

  if (l31 == 0) {
    #pragma unroll
    for (int r = 0; r < 16; ++r)
      part[wn][wm * 32 + (r & 3) + 8 * (r >> 2) + 4 * h] = srow[r];
  }
  __syncthreads();
  if (tid < BM)
    rowinv[tid] = __builtin_amdgcn_rcpf(part[0][tid] + part[1][tid] +
                                        part[2][tid] + part[3][tid]);
  __syncthreads();

  // ---- normalize + coalesced stores ----
  #pragma unroll
  for (int r = 0; r < 16; ++r) {
    const int row = wm * 32 + (r & 3) + 8 * (r >> 2) + 4 * h;
    const float iv = rowinv[row];
    float* o = out + (size_t)(row0 + row) * KC + wn * 128 + l31;
    #pragma unroll
    for (int nt = 0; nt < 4; ++nt)
      o[nt * 32] = acc[nt][r] * iv;
  }
}

extern "C" void kernel_launch(void* const* d_in, const int* in_sizes, int n_in,
                              void* d_out, int out_size, void* d_ws, size_t ws_size,
                              hipStream_t stream) {
  const float* X = (const float*)d_in[0];   // inputs  [131072, 512] fp32
  const float* C = (const float*)d_in[1];   // clusters [512, 512] fp32
  float* out = (float*)d_out;               // [131072, 512] fp32

  short* Bp = (short*)d_ws;                                   // 512 KB packed bf16 clusters
  float* c2 = (float*)((char*)d_ws + (size_t)KC * DIM * 2);   // 2 KB cluster norms

  dec_pack<<<KC, 64, 0, stream>>>(C, Bp, c2);
  dec_main<<<NPTS / BM, 512, 0, stream>>>(X, Bp, c2, out);
}